// Round 9
// baseline (105.143 us; speedup 1.0000x reference)
//
#include <hip/hip_runtime.h>
#include <hip/hip_bf16.h>

// Problem constants (match reference)
#define B_   8
#define NQ_  64     // N_CANDS
#define CTX_ 512    // CTX_LEN
#define DC_  512    // CONTEXT_SIZE
#define DQ_  512    // QUERY_SIZE
#define H_   256    // HIDDEN
#define EPS_ 1e-5f

using short8  = __attribute__((ext_vector_type(8))) short;  // 8 bf16 (4 VGPRs)
using floatx4 = __attribute__((ext_vector_type(4))) float;  // MFMA acc

// 2 fp32 -> packed bf16x2 via v_cvt_pk_bf16_f32 (single instruction on gfx950)
__device__ __forceinline__ unsigned pk2(float x, float y) {
    union { __hip_bfloat162 h; unsigned u; } c;
    c.h = __float22bfloat162_rn(make_float2(x, y));
    return c.u;
}
// 8 fp32 (two float4) -> 16B packed bf16
__device__ __forceinline__ uint4 cvt8u(float4 a, float4 b) {
    uint4 r;
    r.x = pk2(a.x, a.y); r.y = pk2(a.z, a.w);
    r.z = pk2(b.x, b.y); r.w = pk2(b.z, b.w);
    return r;
}

// ---------------------------------------------------------------------------
// Kernel 1: both input GEMMs via bf16 MFMA (R2-exact, measured good).
// Double-buffered LDS + distance-2 register prefetch, ONE barrier per K-step.
// Epilogue: Ec = exp(2*(acc+bias)), Eq = exp(2*acc).
// ---------------------------------------------------------------------------
__global__ __launch_bounds__(256) void gemm_exp(
    const float* __restrict__ ctx, const float* __restrict__ query,
    const float* __restrict__ W_c, const float* __restrict__ b_c,
    const float* __restrict__ W_q,
    float* __restrict__ Ec, float* __restrict__ Eq)
{
    __shared__ unsigned short As[2][32][72];   // double-buffered A tile
    __shared__ unsigned short Bs[2][64][72];   // double-buffered B tile

    const int rt = blockIdx.x;     // 0..143 (128 ctx + 16 query row-tiles)
    const int ct = blockIdx.y;     // 0..3

    const float* A; const float* W; const float* bias; float* outp; int row0;
    if (rt < 128) { A = ctx;   W = W_c; bias = b_c;     outp = Ec; row0 = rt * 32; }
    else          { A = query; W = W_q; bias = nullptr; outp = Eq; row0 = (rt - 128) * 32; }

    const int col0 = ct * 64;
    const int t    = threadIdx.x;
    const int wave = t >> 6;
    const int lane = t & 63;
    const int m  = lane & 15;
    const int kq = lane >> 4;
    const int mh = wave >> 1;      // M-half: rows mh*16..+16
    const int nh = wave & 1;       // N-half: cols nh*32..+32

    // staging ownership: chunk = 8 fp32 contiguous; r = t>>3, s = t&7
    const int sr = t >> 3, ss = t & 7;
    const float* gA  = A + (size_t)(row0 + sr) * 512 + ss * 8;
    const float* gB0 = W + (size_t)(col0 + sr) * 512 + ss * 8;
    const float* gB1 = W + (size_t)(col0 + 32 + sr) * 512 + ss * 8;
    const int lofs = ss * 8;

    floatx4 acc[2] = {};

    // two register banks (compile-time indexed after full unroll)
    float4 rA0[2], rA1[2], rB00[2], rB01[2], rB10[2], rB11[2];

    // prologue: bank0 <- tile 0, bank1 <- tile 1
    rA0[0]  = *(const float4*)(gA);       rA1[0]  = *(const float4*)(gA + 4);
    rB00[0] = *(const float4*)(gB0);      rB01[0] = *(const float4*)(gB0 + 4);
    rB10[0] = *(const float4*)(gB1);      rB11[0] = *(const float4*)(gB1 + 4);
    rA0[1]  = *(const float4*)(gA + 64);  rA1[1]  = *(const float4*)(gA + 68);
    rB00[1] = *(const float4*)(gB0 + 64); rB01[1] = *(const float4*)(gB0 + 68);
    rB10[1] = *(const float4*)(gB1 + 64); rB11[1] = *(const float4*)(gB1 + 68);

    // write buf0 <- bank0 (tile 0)
    *(uint4*)&As[0][sr][lofs]    = cvt8u(rA0[0], rA1[0]);
    *(uint4*)&Bs[0][sr][lofs]    = cvt8u(rB00[0], rB01[0]);
    *(uint4*)&Bs[0][32+sr][lofs] = cvt8u(rB10[0], rB11[0]);

    #pragma unroll
    for (int s = 0; s < 8; ++s) {
        const int cur = s & 1, nxt = cur ^ 1;
        __syncthreads();           // buf[cur] visible; prev readers of buf[nxt] done

        if (s < 6) {               // loads tile s+2 into bank[cur] (regs now free)
            const int k = (s + 2) * 64;
            rA0[cur]  = *(const float4*)(gA + k);      rA1[cur]  = *(const float4*)(gA + k + 4);
            rB00[cur] = *(const float4*)(gB0 + k);     rB01[cur] = *(const float4*)(gB0 + k + 4);
            rB10[cur] = *(const float4*)(gB1 + k);     rB11[cur] = *(const float4*)(gB1 + k + 4);
        }

        #pragma unroll
        for (int kc = 0; kc < 2; ++kc) {
            short8 af  = *(const short8*)&As[cur][mh * 16 + m][kc * 32 + kq * 8];
            short8 b0f = *(const short8*)&Bs[cur][nh * 32 +      m][kc * 32 + kq * 8];
            short8 b1f = *(const short8*)&Bs[cur][nh * 32 + 16 + m][kc * 32 + kq * 8];
            acc[0] = __builtin_amdgcn_mfma_f32_16x16x32_bf16(af, b0f, acc[0], 0, 0, 0);
            acc[1] = __builtin_amdgcn_mfma_f32_16x16x32_bf16(af, b1f, acc[1], 0, 0, 0);
        }

        if (s < 7) {               // write buf[nxt] <- bank[nxt] (tile s+1,
                                   // loaded one full iteration ago)
            *(uint4*)&As[nxt][sr][lofs]    = cvt8u(rA0[nxt], rA1[nxt]);
            *(uint4*)&Bs[nxt][sr][lofs]    = cvt8u(rB00[nxt], rB01[nxt]);
            *(uint4*)&Bs[nxt][32+sr][lofs] = cvt8u(rB10[nxt], rB11[nxt]);
        }
    }

    // Epilogue: D[row=kq*4+i][col=m] per j-tile; write exp(2*(acc+bias))
    #pragma unroll
    for (int j = 0; j < 2; ++j) {
        const int col = col0 + nh * 32 + j * 16 + m;
        const float bb = bias ? bias[col] : 0.f;
        #pragma unroll
        for (int i = 0; i < 4; ++i) {
            const int row = row0 + mh * 16 + kq * 4 + i;
            outp[(size_t)row * H_ + col] = __expf(2.f * (acc[j][i] + bb));
        }
    }
}

// ---------------------------------------------------------------------------
// Kernel 2: scoring. R7/R8 diagnosis: occupancy doubling was NULL -> score
// is bound by per-CU LDS read bandwidth (Ec tile was read 4x per block:
// once per q-wave = 256 KB/block). NEW ownership inversion: wave w owns
// c-strip [w*16,+16); lane = (c-in-strip ci, h-quarter hq). Each ea float4
// is read from LDS ONCE and register-iterated over ALL 4 q -> ea volume
// 256KB -> 64KB/block, LDS instrs 192 -> 96/lane; VALU/trans unchanged.
// qa/w4 become 4-address multicasts (2-way bank alias = free, m136).
// Partial sums reduced across hq via shfl_xor(16,32); lane writes q=hq.
// Staging/chunking/barriers verbatim from the twice-validated structure.
// h-pairing retained: w.x/u + w.y/v = (w.x*v + w.y*u)/(u*v).
// logit = b_o + Sum(W_o) - 2*sum_h W_o[h]/(Ec[c,h]*Eq[q,h]+1).
// Grid 1024 = b(8) x ctile(8: 64c) x qgroup(16: 4q).
// ---------------------------------------------------------------------------
__global__ __launch_bounds__(256) void score_kernel(
    const float* __restrict__ Ec,    // B*CTX*H
    const float* __restrict__ Eqm,   // B*NQ*H
    const float* __restrict__ W_o,   // H
    const float* __restrict__ b_o_p, // scalar
    const float* __restrict__ mask,  // B*CTX
    float* __restrict__ eout)        // B*NQ*CTX
{
    __shared__ float eqs[4][260];    // 4 q rows, stride-260 pad
    __shared__ float wos[H_];
    __shared__ float ecs[64][68];    // 64c x 64h chunk, stride-68 pad
    __shared__ float redS[4];

    const int blk = blockIdx.x;
    const int b     = blk & 7;       // XCD swizzle
    const int ctile = (blk >> 3) & 7;
    const int qg    = blk >> 6;      // 0..15
    const int t  = threadIdx.x;

    // stage eqs: 4 rows x 256; thread t -> row t>>6, cols (t&63)*4
    const float* eqb = Eqm + (size_t)(b * NQ_ + qg * 4) * H_;
    *(float4*)&eqs[t >> 6][(t & 63) * 4] = *(const float4*)(eqb + t * 4);

    const float wo_own = W_o[t];
    wos[t] = wo_own;
    float S = wo_own;
    #pragma unroll
    for (int k = 1; k < 64; k <<= 1) S += __shfl_xor(S, k);
    if ((t & 63) == 0) redS[t >> 6] = S;
    __syncthreads();
    const float base = *b_o_p + redS[0] + redS[1] + redS[2] + redS[3];

    const int w    = t >> 6;         // wave: c-strip [w*16, +16)
    const int lane = t & 63;
    const int ci   = lane & 15;      // c within strip
    const int hq   = lane >> 4;      // h-quarter within chunk (16 h)
    const int c0   = ctile * 64;
    const int crow = w * 16 + ci;    // c within tile
    const float* ec_tile = Ec + (size_t)(b * CTX_ + c0) * H_;
    const int sr = t >> 2, sseg = (t & 3) * 16;       // staging map (verbatim)
    const float* ssrc = ec_tile + (size_t)sr * H_ + sseg;

    float s0 = 0.f, s1 = 0.f, s2 = 0.f, s3 = 0.f;
    for (int hb = 0; hb < 4; ++hb) {
        float4 v0 = *(const float4*)(ssrc + hb * 64);
        float4 v1 = *(const float4*)(ssrc + hb * 64 + 4);
        float4 v2 = *(const float4*)(ssrc + hb * 64 + 8);
        float4 v3 = *(const float4*)(ssrc + hb * 64 + 12);
        __syncthreads();             // prior chunk's compute done
        float* dst = &ecs[sr][sseg];
        *(float4*)(dst)     = v0; *(float4*)(dst + 4)  = v1;
        *(float4*)(dst + 8) = v2; *(float4*)(dst + 12) = v3;
        __syncthreads();
        const int ho = hb * 64;
        #pragma unroll
        for (int h4 = 0; h4 < 4; ++h4) {
            const int hh = hq * 16 + h4 * 4;              // h within chunk
            float4 ea = *(const float4*)&ecs[crow][hh];   // ONE read, 4 q uses
            float4 w4 = *(const float4*)(wos + ho + hh);  // 4-addr multicast
            #pragma unroll
            for (int q = 0; q < 4; ++q) {
                float4 qa = *(const float4*)&eqs[q][ho + hh];  // multicast
                // pair (x,y): one rcp for two h terms
                float ux = fmaf(ea.x, qa.x, 1.f);
                float vx = fmaf(ea.y, qa.y, 1.f);
                float r1 = fmaf(fmaf(w4.y, ux, w4.x * vx),
                                __builtin_amdgcn_rcpf(ux * vx), 0.f);
                // pair (z,w)
                float uz = fmaf(ea.z, qa.z, 1.f);
                float vz = fmaf(ea.w, qa.w, 1.f);
                float r2 = fmaf(fmaf(w4.w, uz, w4.z * vz),
                                __builtin_amdgcn_rcpf(uz * vz), 0.f);
                const float d = r1 + r2;
                if (q == 0) s0 += d;
                else if (q == 1) s1 += d;
                else if (q == 2) s2 += d;
                else s3 += d;
            }
        }
    }

    // reduce partial sums across the 4 h-quarters (lanes ci, ci+16, ci+32, ci+48)
    s0 += __shfl_xor(s0, 16); s0 += __shfl_xor(s0, 32);
    s1 += __shfl_xor(s1, 16); s1 += __shfl_xor(s1, 32);
    s2 += __shfl_xor(s2, 16); s2 += __shfl_xor(s2, 32);
    s3 += __shfl_xor(s3, 16); s3 += __shfl_xor(s3, 32);
    const float sv = (hq == 0) ? s0 : (hq == 1) ? s1 : (hq == 2) ? s2 : s3;

    const int c = c0 + crow;
    const float mk = mask[b * CTX_ + c];
    const int qrow = b * NQ_ + qg * 4 + hq;    // lane writes q = hq
    eout[(size_t)qrow * CTX_ + c] = mk * __expf(base - 2.f * sv);
}

// ---------------------------------------------------------------------------
// Kernel 3: softmax (reference-exact: denom = sum + EPS) + weighted context
// sum (R2-exact, measured good). 512 thr; c split 8-ways; context loads
// batched 8-deep. Grid 512 = b(8) x qg(8) x dq(8).
// ---------------------------------------------------------------------------
__global__ __launch_bounds__(512) void out_kernel(
    const float* __restrict__ eout,    // B*NQ*CTX (mask*exp(logit))
    const float* __restrict__ context, // B*CTX*DC
    float* __restrict__ out,           // B*NQ*DC
    float* __restrict__ wout)          // B*NQ*CTX
{
    __shared__ float ws[CTX_][8];      // q-major weights: 16 KB
    __shared__ float pc[7][64][8];     // partial sums: 14 KB

    const int blk = blockIdx.x;
    const int b  = blk & 7;
    const int qg = (blk >> 3) & 7;
    const int dq = blk >> 6;           // 0..7: d in [dq*64, +64)
    const int t  = threadIdx.x;

    // Phase 1: softmax for the 8 q of this qgroup (one q per wave)
    {
        const int qi = t >> 6;         // 0..7
        const int cl = t & 63;
        const int q = b * NQ_ + qg * 8 + qi;
        const float* erow = eout + (size_t)q * CTX_;
        float ev[8];
        float part = 0.f;
        #pragma unroll
        for (int k = 0; k < 8; ++k) { ev[k] = erow[cl + 64 * k]; part += ev[k]; }
        part += __shfl_xor(part, 1);  part += __shfl_xor(part, 2);
        part += __shfl_xor(part, 4);  part += __shfl_xor(part, 8);
        part += __shfl_xor(part, 16); part += __shfl_xor(part, 32);
        const float inv = 1.f / (part + EPS_);
        #pragma unroll
        for (int k = 0; k < 8; ++k) {
            const float w = ev[k] * inv;
            ws[cl + 64 * k][qi] = w;
            if (dq == 0) wout[(size_t)q * CTX_ + cl + 64 * k] = w;
        }
    }
    __syncthreads();

    // Phase 2: weighted sum; cq = c-eighth, dt = d-lane
    const int cq = t >> 6;             // 0..7
    const int dt = t & 63;
    const int d  = dq * 64 + dt;
    const float* cb = context + ((size_t)(b * CTX_) + cq * 64) * DC_ + d;

    float a0=0,a1=0,a2=0,a3=0,a4=0,a5=0,a6=0,a7=0;
    #pragma unroll 2
    for (int cc = 0; cc < 64; cc += 8) {
        float vv[8];
        #pragma unroll
        for (int k = 0; k < 8; ++k) vv[k] = cb[(size_t)(cc + k) * DC_];
        #pragma unroll
        for (int k = 0; k < 8; ++k) {
            const float4 wA = *(const float4*)&ws[cq * 64 + cc + k][0];  // broadcast
            const float4 wB = *(const float4*)&ws[cq * 64 + cc + k][4];  // broadcast
            a0 += wA.x * vv[k]; a1 += wA.y * vv[k]; a2 += wA.z * vv[k]; a3 += wA.w * vv[k];
            a4 += wB.x * vv[k]; a5 += wB.y * vv[k]; a6 += wB.z * vv[k]; a7 += wB.w * vv[k];
        }
    }
    if (cq) {
        float4* p = (float4*)pc[cq - 1][dt];
        p[0] = make_float4(a0, a1, a2, a3);
        p[1] = make_float4(a4, a5, a6, a7);
    }
    __syncthreads();
    if (cq == 0) {
        float r[8] = {a0, a1, a2, a3, a4, a5, a6, a7};
        #pragma unroll
        for (int pI = 0; pI < 7; ++pI) {
            const float4 xA = *(const float4*)&pc[pI][dt][0];
            const float4 xB = *(const float4*)&pc[pI][dt][4];
            r[0] += xA.x; r[1] += xA.y; r[2] += xA.z; r[3] += xA.w;
            r[4] += xB.x; r[5] += xB.y; r[6] += xB.z; r[7] += xB.w;
        }
        const int qbase = b * NQ_ + qg * 8;
        #pragma unroll
        for (int j = 0; j < 8; ++j)
            out[(size_t)(qbase + j) * DC_ + d] = r[j];
    }
}

extern "C" void kernel_launch(void* const* d_in, const int* in_sizes, int n_in,
                              void* d_out, int out_size, void* d_ws, size_t ws_size,
                              hipStream_t stream) {
    const float* query   = (const float*)d_in[0];  // B,NQ,DQ
    const float* context = (const float*)d_in[1];  // B,CTX,DC
    const float* mask    = (const float*)d_in[2];  // B,CTX
    const float* W_c     = (const float*)d_in[3];  // H,DC
    const float* b_c     = (const float*)d_in[4];  // H
    const float* W_q     = (const float*)d_in[5];  // H,DQ
    const float* W_o     = (const float*)d_in[6];  // H
    const float* b_o     = (const float*)d_in[7];  // scalar

    float* out  = (float*)d_out;                   // B,NQ,DC
    float* wout = out + (size_t)B_ * NQ_ * DC_;    // B,NQ,CTX

    float* Ec   = (float*)d_ws;                        // 4 MB: exp(2*res_c)
    float* Eq   = Ec + (size_t)B_ * CTX_ * H_;         // 512 KB: exp(2*res_q)
    float* eout = Eq + (size_t)B_ * NQ_ * H_;          // 1 MB: mask*exp(logit)

    gemm_exp<<<dim3(144, 4), 256, 0, stream>>>(
        context, query, W_c, b_c, W_q, Ec, Eq);
    score_kernel<<<1024, 256, 0, stream>>>(
        Ec, Eq, W_o, b_o, mask, eout);
    out_kernel<<<512, 512, 0, stream>>>(
        eout, context, out, wout);
}

// Round 10
// 102.747 us; speedup vs baseline: 1.0233x; 1.0233x over previous
//
#include <hip/hip_runtime.h>
#include <hip/hip_bf16.h>

// Problem constants (match reference)
#define B_   8
#define NQ_  64     // N_CANDS
#define CTX_ 512    // CTX_LEN
#define DC_  512    // CONTEXT_SIZE
#define DQ_  512    // QUERY_SIZE
#define H_   256    // HIDDEN
#define EPS_ 1e-5f

using short8  = __attribute__((ext_vector_type(8))) short;  // 8 bf16 (4 VGPRs)
using floatx4 = __attribute__((ext_vector_type(4))) float;  // MFMA acc

// 2 fp32 -> packed bf16x2 via v_cvt_pk_bf16_f32 (single instruction on gfx950)
__device__ __forceinline__ unsigned pk2(float x, float y) {
    union { __hip_bfloat162 h; unsigned u; } c;
    c.h = __float22bfloat162_rn(make_float2(x, y));
    return c.u;
}
// 8 fp32 (two float4) -> 16B packed bf16
__device__ __forceinline__ uint4 cvt8u(float4 a, float4 b) {
    uint4 r;
    r.x = pk2(a.x, a.y); r.y = pk2(a.z, a.w);
    r.z = pk2(b.x, b.y); r.w = pk2(b.z, b.w);
    return r;
}

// ---------------------------------------------------------------------------
// Kernel 1: both input GEMMs via bf16 MFMA (R2-exact, measured good).
// Double-buffered LDS + distance-2 register prefetch, ONE barrier per K-step.
// Epilogue: Ec = exp(2*(acc+bias)), Eq = exp(2*acc).
// ---------------------------------------------------------------------------
__global__ __launch_bounds__(256) void gemm_exp(
    const float* __restrict__ ctx, const float* __restrict__ query,
    const float* __restrict__ W_c, const float* __restrict__ b_c,
    const float* __restrict__ W_q,
    float* __restrict__ Ec, float* __restrict__ Eq)
{
    __shared__ unsigned short As[2][32][72];   // double-buffered A tile
    __shared__ unsigned short Bs[2][64][72];   // double-buffered B tile

    const int rt = blockIdx.x;     // 0..143 (128 ctx + 16 query row-tiles)
    const int ct = blockIdx.y;     // 0..3

    const float* A; const float* W; const float* bias; float* outp; int row0;
    if (rt < 128) { A = ctx;   W = W_c; bias = b_c;     outp = Ec; row0 = rt * 32; }
    else          { A = query; W = W_q; bias = nullptr; outp = Eq; row0 = (rt - 128) * 32; }

    const int col0 = ct * 64;
    const int t    = threadIdx.x;
    const int wave = t >> 6;
    const int lane = t & 63;
    const int m  = lane & 15;
    const int kq = lane >> 4;
    const int mh = wave >> 1;      // M-half: rows mh*16..+16
    const int nh = wave & 1;       // N-half: cols nh*32..+32

    // staging ownership: chunk = 8 fp32 contiguous; r = t>>3, s = t&7
    const int sr = t >> 3, ss = t & 7;
    const float* gA  = A + (size_t)(row0 + sr) * 512 + ss * 8;
    const float* gB0 = W + (size_t)(col0 + sr) * 512 + ss * 8;
    const float* gB1 = W + (size_t)(col0 + 32 + sr) * 512 + ss * 8;
    const int lofs = ss * 8;

    floatx4 acc[2] = {};

    // two register banks (compile-time indexed after full unroll)
    float4 rA0[2], rA1[2], rB00[2], rB01[2], rB10[2], rB11[2];

    // prologue: bank0 <- tile 0, bank1 <- tile 1
    rA0[0]  = *(const float4*)(gA);       rA1[0]  = *(const float4*)(gA + 4);
    rB00[0] = *(const float4*)(gB0);      rB01[0] = *(const float4*)(gB0 + 4);
    rB10[0] = *(const float4*)(gB1);      rB11[0] = *(const float4*)(gB1 + 4);
    rA0[1]  = *(const float4*)(gA + 64);  rA1[1]  = *(const float4*)(gA + 68);
    rB00[1] = *(const float4*)(gB0 + 64); rB01[1] = *(const float4*)(gB0 + 68);
    rB10[1] = *(const float4*)(gB1 + 64); rB11[1] = *(const float4*)(gB1 + 68);

    // write buf0 <- bank0 (tile 0)
    *(uint4*)&As[0][sr][lofs]    = cvt8u(rA0[0], rA1[0]);
    *(uint4*)&Bs[0][sr][lofs]    = cvt8u(rB00[0], rB01[0]);
    *(uint4*)&Bs[0][32+sr][lofs] = cvt8u(rB10[0], rB11[0]);

    #pragma unroll
    for (int s = 0; s < 8; ++s) {
        const int cur = s & 1, nxt = cur ^ 1;
        __syncthreads();           // buf[cur] visible; prev readers of buf[nxt] done

        if (s < 6) {               // loads tile s+2 into bank[cur] (regs now free)
            const int k = (s + 2) * 64;
            rA0[cur]  = *(const float4*)(gA + k);      rA1[cur]  = *(const float4*)(gA + k + 4);
            rB00[cur] = *(const float4*)(gB0 + k);     rB01[cur] = *(const float4*)(gB0 + k + 4);
            rB10[cur] = *(const float4*)(gB1 + k);     rB11[cur] = *(const float4*)(gB1 + k + 4);
        }

        #pragma unroll
        for (int kc = 0; kc < 2; ++kc) {
            short8 af  = *(const short8*)&As[cur][mh * 16 + m][kc * 32 + kq * 8];
            short8 b0f = *(const short8*)&Bs[cur][nh * 32 +      m][kc * 32 + kq * 8];
            short8 b1f = *(const short8*)&Bs[cur][nh * 32 + 16 + m][kc * 32 + kq * 8];
            acc[0] = __builtin_amdgcn_mfma_f32_16x16x32_bf16(af, b0f, acc[0], 0, 0, 0);
            acc[1] = __builtin_amdgcn_mfma_f32_16x16x32_bf16(af, b1f, acc[1], 0, 0, 0);
        }

        if (s < 7) {               // write buf[nxt] <- bank[nxt] (tile s+1,
                                   // loaded one full iteration ago)
            *(uint4*)&As[nxt][sr][lofs]    = cvt8u(rA0[nxt], rA1[nxt]);
            *(uint4*)&Bs[nxt][sr][lofs]    = cvt8u(rB00[nxt], rB01[nxt]);
            *(uint4*)&Bs[nxt][32+sr][lofs] = cvt8u(rB10[nxt], rB11[nxt]);
        }
    }

    // Epilogue: D[row=kq*4+i][col=m] per j-tile; write exp(2*(acc+bias))
    #pragma unroll
    for (int j = 0; j < 2; ++j) {
        const int col = col0 + nh * 32 + j * 16 + m;
        const float bb = bias ? bias[col] : 0.f;
        #pragma unroll
        for (int i = 0; i < 4; ++i) {
            const int row = row0 + mh * 16 + kq * 4 + i;
            outp[(size_t)row * H_ + col] = __expf(2.f * (acc[j][i] + bb));
        }
    }
}

// ---------------------------------------------------------------------------
// Kernel 2: scoring. R7-R9 established: occupancy x2 null, per-thread-work /2
// null, LDS volume /4 null. Common factor in all nulled variants: the
// barriered 4-chunk staging skeleton (8 syncthreads + 4 exposed L2->LDS
// round-trips per block). NEW: remove it. With the R9 lane map (wave owns
// c-strip[16]; lane = ci + 16*hq) a wave's global float4 read is coalesced
// (16 rows x 64B-aligned segments; h4 unroll consumes full lines via L1,
// unlike R3's 64-line-per-load mapping that regressed). Score is now a
// ZERO-main-loop-barrier streaming kernel: 16 unrolled independent global
// loads per thread (L2-resident Ec), LDS only for small eqs/wos multicast
// tables, shfl_xor epilogue. Arithmetic bit-identical to R9.
// logit = b_o + Sum(W_o) - 2*sum_h W_o[h]/(Ec[c,h]*Eq[q,h]+1).
// Grid 1024 = b(8) x ctile(8: 64c) x qgroup(16: 4q).
// ---------------------------------------------------------------------------
__global__ __launch_bounds__(256) void score_kernel(
    const float* __restrict__ Ec,    // B*CTX*H
    const float* __restrict__ Eqm,   // B*NQ*H
    const float* __restrict__ W_o,   // H
    const float* __restrict__ b_o_p, // scalar
    const float* __restrict__ mask,  // B*CTX
    float* __restrict__ eout)        // B*NQ*CTX
{
    __shared__ float eqs[4][260];    // 4 q rows, stride-260 pad
    __shared__ float wos[H_];
    __shared__ float redS[4];

    const int blk = blockIdx.x;
    const int b     = blk & 7;       // XCD swizzle
    const int ctile = (blk >> 3) & 7;
    const int qg    = blk >> 6;      // 0..15
    const int t  = threadIdx.x;

    // stage eqs: 4 rows x 256; thread t -> row t>>6, cols (t&63)*4
    const float* eqb = Eqm + (size_t)(b * NQ_ + qg * 4) * H_;
    *(float4*)&eqs[t >> 6][(t & 63) * 4] = *(const float4*)(eqb + t * 4);

    const float wo_own = W_o[t];
    wos[t] = wo_own;
    float S = wo_own;
    #pragma unroll
    for (int k = 1; k < 64; k <<= 1) S += __shfl_xor(S, k);
    if ((t & 63) == 0) redS[t >> 6] = S;
    __syncthreads();                 // the ONLY barrier
    const float base = *b_o_p + redS[0] + redS[1] + redS[2] + redS[3];

    const int w    = t >> 6;         // wave: c-strip [w*16, +16)
    const int lane = t & 63;
    const int ci   = lane & 15;      // c within strip
    const int hq   = lane >> 4;      // h-quarter within chunk (16 h)
    const int c0   = ctile * 64;
    const int crow = w * 16 + ci;    // c within tile
    // lane's own Ec row, direct from L2 (coalesced across the wave)
    const float* er = Ec + (size_t)(b * CTX_ + c0 + crow) * H_;

    float s0 = 0.f, s1 = 0.f, s2 = 0.f, s3 = 0.f;
    #pragma unroll
    for (int hb = 0; hb < 4; ++hb) {
        const int ho = hb * 64;
        #pragma unroll
        for (int h4 = 0; h4 < 4; ++h4) {
            const int hh = hq * 16 + h4 * 4;              // h within chunk
            float4 ea = *(const float4*)(er + ho + hh);   // global, L2-hot
            float4 w4 = *(const float4*)(wos + hh + (ho)); // 4-addr multicast
            #pragma unroll
            for (int q = 0; q < 4; ++q) {
                float4 qa = *(const float4*)&eqs[q][ho + hh];  // multicast
                // pair (x,y): one rcp for two h terms
                float ux = fmaf(ea.x, qa.x, 1.f);
                float vx = fmaf(ea.y, qa.y, 1.f);
                float r1 = fmaf(fmaf(w4.y, ux, w4.x * vx),
                                __builtin_amdgcn_rcpf(ux * vx), 0.f);
                // pair (z,w)
                float uz = fmaf(ea.z, qa.z, 1.f);
                float vz = fmaf(ea.w, qa.w, 1.f);
                float r2 = fmaf(fmaf(w4.w, uz, w4.z * vz),
                                __builtin_amdgcn_rcpf(uz * vz), 0.f);
                const float d = r1 + r2;
                if (q == 0) s0 += d;
                else if (q == 1) s1 += d;
                else if (q == 2) s2 += d;
                else s3 += d;
            }
        }
    }

    // reduce partial sums across the 4 h-quarters (lanes ci, ci+16, ci+32, ci+48)
    s0 += __shfl_xor(s0, 16); s0 += __shfl_xor(s0, 32);
    s1 += __shfl_xor(s1, 16); s1 += __shfl_xor(s1, 32);
    s2 += __shfl_xor(s2, 16); s2 += __shfl_xor(s2, 32);
    s3 += __shfl_xor(s3, 16); s3 += __shfl_xor(s3, 32);
    const float sv = (hq == 0) ? s0 : (hq == 1) ? s1 : (hq == 2) ? s2 : s3;

    const int c = c0 + crow;
    const float mk = mask[b * CTX_ + c];
    const int qrow = b * NQ_ + qg * 4 + hq;    // lane writes q = hq
    eout[(size_t)qrow * CTX_ + c] = mk * __expf(base - 2.f * sv);
}

// ---------------------------------------------------------------------------
// Kernel 3: softmax (reference-exact: denom = sum + EPS) + weighted context
// sum (R2-exact, measured good). 512 thr; c split 8-ways; context loads
// batched 8-deep. Grid 512 = b(8) x qg(8) x dq(8).
// ---------------------------------------------------------------------------
__global__ __launch_bounds__(512) void out_kernel(
    const float* __restrict__ eout,    // B*NQ*CTX (mask*exp(logit))
    const float* __restrict__ context, // B*CTX*DC
    float* __restrict__ out,           // B*NQ*DC
    float* __restrict__ wout)          // B*NQ*CTX
{
    __shared__ float ws[CTX_][8];      // q-major weights: 16 KB
    __shared__ float pc[7][64][8];     // partial sums: 14 KB

    const int blk = blockIdx.x;
    const int b  = blk & 7;
    const int qg = (blk >> 3) & 7;
    const int dq = blk >> 6;           // 0..7: d in [dq*64, +64)
    const int t  = threadIdx.x;

    // Phase 1: softmax for the 8 q of this qgroup (one q per wave)
    {
        const int qi = t >> 6;         // 0..7
        const int cl = t & 63;
        const int q = b * NQ_ + qg * 8 + qi;
        const float* erow = eout + (size_t)q * CTX_;
        float ev[8];
        float part = 0.f;
        #pragma unroll
        for (int k = 0; k < 8; ++k) { ev[k] = erow[cl + 64 * k]; part += ev[k]; }
        part += __shfl_xor(part, 1);  part += __shfl_xor(part, 2);
        part += __shfl_xor(part, 4);  part += __shfl_xor(part, 8);
        part += __shfl_xor(part, 16); part += __shfl_xor(part, 32);
        const float inv = 1.f / (part + EPS_);
        #pragma unroll
        for (int k = 0; k < 8; ++k) {
            const float w = ev[k] * inv;
            ws[cl + 64 * k][qi] = w;
            if (dq == 0) wout[(size_t)q * CTX_ + cl + 64 * k] = w;
        }
    }
    __syncthreads();

    // Phase 2: weighted sum; cq = c-eighth, dt = d-lane
    const int cq = t >> 6;             // 0..7
    const int dt = t & 63;
    const int d  = dq * 64 + dt;
    const float* cb = context + ((size_t)(b * CTX_) + cq * 64) * DC_ + d;

    float a0=0,a1=0,a2=0,a3=0,a4=0,a5=0,a6=0,a7=0;
    #pragma unroll 2
    for (int cc = 0; cc < 64; cc += 8) {
        float vv[8];
        #pragma unroll
        for (int k = 0; k < 8; ++k) vv[k] = cb[(size_t)(cc + k) * DC_];
        #pragma unroll
        for (int k = 0; k < 8; ++k) {
            const float4 wA = *(const float4*)&ws[cq * 64 + cc + k][0];  // broadcast
            const float4 wB = *(const float4*)&ws[cq * 64 + cc + k][4];  // broadcast
            a0 += wA.x * vv[k]; a1 += wA.y * vv[k]; a2 += wA.z * vv[k]; a3 += wA.w * vv[k];
            a4 += wB.x * vv[k]; a5 += wB.y * vv[k]; a6 += wB.z * vv[k]; a7 += wB.w * vv[k];
        }
    }
    if (cq) {
        float4* p = (float4*)pc[cq - 1][dt];
        p[0] = make_float4(a0, a1, a2, a3);
        p[1] = make_float4(a4, a5, a6, a7);
    }
    __syncthreads();
    if (cq == 0) {
        float r[8] = {a0, a1, a2, a3, a4, a5, a6, a7};
        #pragma unroll
        for (int pI = 0; pI < 7; ++pI) {
            const float4 xA = *(const float4*)&pc[pI][dt][0];
            const float4 xB = *(const float4*)&pc[pI][dt][4];
            r[0] += xA.x; r[1] += xA.y; r[2] += xA.z; r[3] += xA.w;
            r[4] += xB.x; r[5] += xB.y; r[6] += xB.z; r[7] += xB.w;
        }
        const int qbase = b * NQ_ + qg * 8;
        #pragma unroll
        for (int j = 0; j < 8; ++j)
            out[(size_t)(qbase + j) * DC_ + d] = r[j];
    }
}

extern "C" void kernel_launch(void* const* d_in, const int* in_sizes, int n_in,
                              void* d_out, int out_size, void* d_ws, size_t ws_size,
                              hipStream_t stream) {
    const float* query   = (const float*)d_in[0];  // B,NQ,DQ
    const float* context = (const float*)d_in[1];  // B,CTX,DC
    const float* mask    = (const float*)d_in[2];  // B,CTX
    const float* W_c     = (const float*)d_in[3];  // H,DC
    const float* b_c     = (const float*)d_in[4];  // H
    const float* W_q     = (const float*)d_in[5];  // H,DQ
    const float* W_o     = (const float*)d_in[6];  // H
    const float* b_o     = (const float*)d_in[7];  // scalar

    float* out  = (float*)d_out;                   // B,NQ,DC
    float* wout = out + (size_t)B_ * NQ_ * DC_;    // B,NQ,CTX

    float* Ec   = (float*)d_ws;                        // 4 MB: exp(2*res_c)
    float* Eq   = Ec + (size_t)B_ * CTX_ * H_;         // 512 KB: exp(2*res_q)
    float* eout = Eq + (size_t)B_ * NQ_ * H_;          // 1 MB: mask*exp(logit)

    gemm_exp<<<dim3(144, 4), 256, 0, stream>>>(
        context, query, W_c, b_c, W_q, Ec, Eq);
    score_kernel<<<1024, 256, 0, stream>>>(
        Ec, Eq, W_o, b_o, mask, eout);
    out_kernel<<<512, 512, 0, stream>>>(
        eout, context, out, wout);
}